// Round 3
// baseline (112.746 us; speedup 1.0000x reference)
//
#include <hip/hip_runtime.h>

// Elementwise: out = sqrt((x + 5) * 2 - 3) = sqrt(2x + 7), fp32 in / fp32 out.
// Memory-bound streaming: 536.9 MB traffic. Target ~6.3 TB/s -> ~85-95 us.
// 4x unrolled grid-stride loop (4 independent 16B loads in flight/thread) +
// nontemporal hints (zero reuse, skip cache allocation).
// NOTE: __builtin_nontemporal_* needs a NATIVE vector type, not HIP float4.

typedef float f4 __attribute__((ext_vector_type(4)));

__global__ void __launch_bounds__(256) elemwise_sqrt_kernel(
        const f4* __restrict__ in4,
        f4* __restrict__ out4,
        int n4) {
    const int tid = blockIdx.x * blockDim.x + threadIdx.x;
    const int stride = gridDim.x * blockDim.x;

    int i = tid;
    for (; i + 3 * stride < n4; i += 4 * stride) {
        f4 v0 = __builtin_nontemporal_load(&in4[i]);
        f4 v1 = __builtin_nontemporal_load(&in4[i + stride]);
        f4 v2 = __builtin_nontemporal_load(&in4[i + 2 * stride]);
        f4 v3 = __builtin_nontemporal_load(&in4[i + 3 * stride]);

        f4 r0, r1, r2, r3;
        #pragma unroll
        for (int j = 0; j < 4; ++j) {
            r0[j] = sqrtf(fmaf(v0[j], 2.0f, 7.0f));
            r1[j] = sqrtf(fmaf(v1[j], 2.0f, 7.0f));
            r2[j] = sqrtf(fmaf(v2[j], 2.0f, 7.0f));
            r3[j] = sqrtf(fmaf(v3[j], 2.0f, 7.0f));
        }

        __builtin_nontemporal_store(r0, &out4[i]);
        __builtin_nontemporal_store(r1, &out4[i + stride]);
        __builtin_nontemporal_store(r2, &out4[i + 2 * stride]);
        __builtin_nontemporal_store(r3, &out4[i + 3 * stride]);
    }
    // Tail (not taken for 8192^2, but correct for any size).
    for (; i < n4; i += stride) {
        f4 v = __builtin_nontemporal_load(&in4[i]);
        f4 r;
        #pragma unroll
        for (int j = 0; j < 4; ++j) r[j] = sqrtf(fmaf(v[j], 2.0f, 7.0f));
        __builtin_nontemporal_store(r, &out4[i]);
    }
}

extern "C" void kernel_launch(void* const* d_in, const int* in_sizes, int n_in,
                              void* d_out, int out_size, void* d_ws, size_t ws_size,
                              hipStream_t stream) {
    const f4* in4 = (const f4*)d_in[0];
    f4* out4 = (f4*)d_out;
    int n = in_sizes[0];          // 8192*8192 = 67108864, divisible by 4
    int n4 = n / 4;               // 16777216 float4s

    const int block = 256;
    int grid = (n4 + block - 1) / block;
    const int max_grid = 2048;    // 256 CUs x 8 blocks/CU; 32 float4/thread
    if (grid > max_grid) grid = max_grid;

    elemwise_sqrt_kernel<<<grid, block, 0, stream>>>(in4, out4, n4);
}

// Round 4
// 93.648 us; speedup vs baseline: 1.2039x; 1.2039x over previous
//
#include <hip/hip_runtime.h>

// Elementwise: out = sqrt((x + 5) * 2 - 3) = sqrt(2x + 7), fp32 in / fp32 out.
// Memory-bound streaming: 536.9 MB traffic.
// R4: flat kernel — one float4 per thread, no grid-stride loop. Matches the
// shape of the rocclr fill kernel that sustains ~7 TB/s write-only on this
// box. 65536 workgroups of 256; minimal VGPRs; maximal TLP.

typedef float f4 __attribute__((ext_vector_type(4)));

__global__ void __launch_bounds__(256) elemwise_sqrt_flat(
        const f4* __restrict__ in4,
        f4* __restrict__ out4,
        int n4) {
    int i = blockIdx.x * 256 + threadIdx.x;
    if (i < n4) {
        f4 v = in4[i];
        f4 r;
        #pragma unroll
        for (int j = 0; j < 4; ++j) r[j] = sqrtf(fmaf(v[j], 2.0f, 7.0f));
        out4[i] = r;
    }
}

extern "C" void kernel_launch(void* const* d_in, const int* in_sizes, int n_in,
                              void* d_out, int out_size, void* d_ws, size_t ws_size,
                              hipStream_t stream) {
    const f4* in4 = (const f4*)d_in[0];
    f4* out4 = (f4*)d_out;
    int n = in_sizes[0];          // 8192*8192 = 67108864, divisible by 4
    int n4 = n / 4;               // 16777216 float4s -> 65536 blocks of 256

    const int block = 256;
    int grid = (n4 + block - 1) / block;

    elemwise_sqrt_flat<<<grid, block, 0, stream>>>(in4, out4, n4);
}

// Round 5
// 84.920 us; speedup vs baseline: 1.3277x; 1.1028x over previous
//
#include <hip/hip_runtime.h>

// Elementwise: out = sqrt((x + 5) * 2 - 3) = sqrt(2x + 7), fp32 in / fp32 out.
// Memory-bound streaming: 536.9 MB traffic.
// R5: flat kernel (R4 winner, 93.6 us / 5.73 TB/s) + nontemporal load/store.
// Streams are touch-once: NT skips L2/L3 line allocation so the write stream
// doesn't contend with read-stream tags. Single-variable change vs R4.

typedef float f4 __attribute__((ext_vector_type(4)));

__global__ void __launch_bounds__(256) elemwise_sqrt_flat_nt(
        const f4* __restrict__ in4,
        f4* __restrict__ out4,
        int n4) {
    int i = blockIdx.x * 256 + threadIdx.x;
    if (i < n4) {
        f4 v = __builtin_nontemporal_load(&in4[i]);
        f4 r;
        #pragma unroll
        for (int j = 0; j < 4; ++j) r[j] = sqrtf(fmaf(v[j], 2.0f, 7.0f));
        __builtin_nontemporal_store(r, &out4[i]);
    }
}

extern "C" void kernel_launch(void* const* d_in, const int* in_sizes, int n_in,
                              void* d_out, int out_size, void* d_ws, size_t ws_size,
                              hipStream_t stream) {
    const f4* in4 = (const f4*)d_in[0];
    f4* out4 = (f4*)d_out;
    int n = in_sizes[0];          // 8192*8192 = 67108864, divisible by 4
    int n4 = n / 4;               // 16777216 float4s -> 65536 blocks of 256

    const int block = 256;
    int grid = (n4 + block - 1) / block;

    elemwise_sqrt_flat_nt<<<grid, block, 0, stream>>>(in4, out4, n4);
}